// Round 8
// baseline (1157.748 us; speedup 1.0000x reference)
//
#include <hip/hip_runtime.h>

#define NB      16
#define NPTS    4096
#define NPOINT  1024
#define NSAMPLE 32
#define NCHUNK  1024  // 16-query chunks: c = s16*16 + b

typedef float v2f __attribute__((ext_vector_type(2)));

// ---- packed f32 ops (VOP3P, exact IEEE RN per half; NOT fused) ----
__device__ __forceinline__ v2f pk_add(v2f a, v2f b) {
  v2f d;
  asm("v_pk_add_f32 %0, %1, %2" : "=v"(d) : "v"(a), "v"(b));
  return d;
}
__device__ __forceinline__ v2f pk_mul(v2f a, v2f b) {
  v2f d;
  asm("v_pk_mul_f32 %0, %1, %2" : "=v"(d) : "v"(a), "v"(b));
  return d;
}
__device__ __forceinline__ float fnegx(float x) {  // exact bit-flip negation
  return __int_as_float(__float_as_int(x) ^ 0x80000000);
}

// ---------------- DPP / swizzle u64-key max helpers ----------------
template <int C>
__device__ __forceinline__ int dppi(int v) {
  return __builtin_amdgcn_update_dpp(0, v, C, 0xf, 0xf, true);
}

template <int C>
__device__ __forceinline__ unsigned long long dppmax_u64(unsigned long long k) {
  int lo = dppi<C>((int)(unsigned)k);
  int hi = dppi<C>((int)(k >> 32));
  unsigned long long o = ((unsigned long long)(unsigned)hi << 32) | (unsigned)lo;
  return o > k ? o : k;
}

__device__ __forceinline__ unsigned long long swzmax16_u64(unsigned long long k) {
  int lo = __builtin_amdgcn_ds_swizzle((int)(unsigned)k, 0x401F);  // lane ^= 16
  int hi = __builtin_amdgcn_ds_swizzle((int)(k >> 32), 0x401F);
  unsigned long long o = ((unsigned long long)(unsigned)hi << 32) | (unsigned)lo;
  return o > k ? o : k;
}

// shared memory: FPS view / consumer view; padded to 82048 B so that
// 2 blocks can NEVER co-reside on a CU (163840/82048 = 1) -- R7 showed
// co-residency steals VALU issue from the latency-critical FPS waves.
union SharedU {
  struct {
    float lx[NPTS], ly[NPTS], lz[NPTS];
    unsigned long long part[2][16];
  } f;
  struct {
    float sw[4096];          // staged W0[3:67]
    int sidx[16][NSAMPLE];   // ball-query result for the current chunk
  } c;
  char pad[82048];
};

// ---------------------------------------------------------------------------
// Cooperative mega-kernel (1 block/CU guaranteed by LDS size; co-residency
// of all 256 blocks guaranteed by cooperative launch).
// Blocks 0..15: FPS v6 core; centers stored directly to out_xyz; every 64
//   centers: release-store flag[b][g] (agent scope) -> consumers may start.
// Blocks 16..255: P1 slice first (~15us, done before first flag), then
//   grid-stride over 1024 chunks of 16 queries ordered by center index:
//   acquire flag -> ballq (2 q/wave) -> barrier -> MLP+maxpool -> barrier.
// ---------------------------------------------------------------------------
__global__ __launch_bounds__(512) void mega_kernel(
    const float* __restrict__ xyz, const float* __restrict__ pts,
    const float* __restrict__ W0, const float* __restrict__ b0,
    const float* __restrict__ W1, const float* __restrict__ b1,
    const float* __restrict__ W2, const float* __restrict__ b2,
    float* __restrict__ out_xyz, float* __restrict__ out_np,
    float* __restrict__ out_idx, float* __restrict__ P1,
    int* __restrict__ flags, int* __restrict__ p1done) {
  __shared__ SharedU sm;
  const int t = threadIdx.x;
  const int wv = t >> 6, lane = t & 63;

  if (blockIdx.x < NB) {
    // ============================ FPS (v6 core) ============================
    const int b = blockIdx.x;
    const float* g = xyz + (size_t)b * NPTS * 3;
    for (int j = t; j < NPTS; j += 512) {
      sm.f.lx[j] = g[3 * j]; sm.f.ly[j] = g[3 * j + 1]; sm.f.lz[j] = g[3 * j + 2];
    }
    __syncthreads();
    v2f px2[4], py2[4], pz2[4], mind2[4];
    unsigned nlo[8];
#pragma unroll
    for (int p = 0; p < 4; ++p) {
      const int j0 = t + 512 * (2 * p);
      px2[p] = (v2f){sm.f.lx[j0], sm.f.lx[j0 + 512]};
      py2[p] = (v2f){sm.f.ly[j0], sm.f.ly[j0 + 512]};
      pz2[p] = (v2f){sm.f.lz[j0], sm.f.lz[j0 + 512]};
      mind2[p] = (v2f){1e10f, 1e10f};
      nlo[2 * p] = ~(unsigned)j0;
      nlo[2 * p + 1] = ~(unsigned)(j0 + 512);
    }
    float cx = sm.f.lx[0], cy = sm.f.ly[0], cz = sm.f.lz[0];
    float* ob = out_xyz + (size_t)b * NPOINT * 3;
    for (int it = 0; it < NPOINT; ++it) {
      if (t == 0) {
        ob[3 * it] = cx; ob[3 * it + 1] = cy; ob[3 * it + 2] = cz;
        if ((it & 63) == 63)  // publish centers [g*64, g*64+64)
          __hip_atomic_store(&flags[b * 16 + (it >> 6)], 1, __ATOMIC_RELEASE,
                             __HIP_MEMORY_SCOPE_AGENT);
      }
      const float ncx = fnegx(cx), ncy = fnegx(cy), ncz = fnegx(cz);
      const v2f ncxx = (v2f){ncx, ncx};
      const v2f ncyy = (v2f){ncy, ncy};
      const v2f nczz = (v2f){ncz, ncz};
#pragma unroll
      for (int p = 0; p < 4; ++p) {
        const v2f dx = pk_add(px2[p], ncxx);
        const v2f dy = pk_add(py2[p], ncyy);
        const v2f dz = pk_add(pz2[p], nczz);
        const v2f xx = pk_mul(dx, dx);
        const v2f yy = pk_mul(dy, dy);
        const v2f zz = pk_mul(dz, dz);
        v2f s = pk_add(xx, yy);
        s = pk_add(s, zz);
        mind2[p].x = fminf(mind2[p].x, s.x);
        mind2[p].y = fminf(mind2[p].y, s.y);
      }
      unsigned long long k[8];
#pragma unroll
      for (int p = 0; p < 4; ++p) {
        k[2 * p] = ((unsigned long long)__float_as_uint(mind2[p].x) << 32) | nlo[2 * p];
        k[2 * p + 1] =
            ((unsigned long long)__float_as_uint(mind2[p].y) << 32) | nlo[2 * p + 1];
      }
#pragma unroll
      for (int s = 4; s; s >>= 1)
#pragma unroll
        for (int i = 0; i < s; ++i) k[i] = k[i] > k[i + s] ? k[i] : k[i + s];
      unsigned long long key = k[0];
      key = dppmax_u64<0xB1>(key);   // xor 1
      key = dppmax_u64<0x4E>(key);   // xor 2
      key = dppmax_u64<0x141>(key);  // half-mirror (covers 8)
      key = dppmax_u64<0x140>(key);  // mirror (covers 16)
      key = swzmax16_u64(key);       // xor 16 -> 32-lane uniform
      const int buf = it & 1;
      if ((lane & 31) == 0) sm.f.part[buf][(t >> 6) * 2 + (lane >> 5)] = key;
      __syncthreads();
      unsigned long long rk = sm.f.part[buf][lane & 15];
      rk = dppmax_u64<0xB1>(rk);
      rk = dppmax_u64<0x4E>(rk);
      rk = dppmax_u64<0x141>(rk);
      rk = dppmax_u64<0x140>(rk);
      const unsigned idx = ~(unsigned)rk;  // winner (block-uniform)
      cx = sm.f.lx[idx]; cy = sm.f.ly[idx]; cz = sm.f.lz[idx];
    }
  } else {
    // ============================ CONSUMERS ============================
    const int nb = (int)gridDim.x - NB;
    const int cb = (int)blockIdx.x - NB;
    // ---- stage W0[3:67] ----
    {
      const float4* w4 = (const float4*)(W0 + 192);
      float4* s4 = (float4*)sm.c.sw;
      s4[t] = w4[t]; s4[t + 512] = w4[t + 512];
    }
    __syncthreads();
    // ---- P1 slice: rows [cb*rows_per, ...) ----
    const int rows_per = (NPTS * NB + nb - 1) / nb;
    const int r0 = cb * rows_per;
    const int r1 = min(r0 + rows_per, NPTS * NB);
    for (int r = r0 + t; r < r1; r += 512) {
      const float* prow = pts + (size_t)r * 64;
      float acc[64];
#pragma unroll
      for (int d = 0; d < 64; ++d) acc[d] = 0.0f;
#pragma unroll
      for (int cq = 0; cq < 16; ++cq) {
        const float4 p4 = *(const float4*)(prow + cq * 4);
        const float pv[4] = {p4.x, p4.y, p4.z, p4.w};
#pragma unroll
        for (int u = 0; u < 4; ++u) {
          const int cc = cq * 4 + u;
#pragma unroll
          for (int d4 = 0; d4 < 16; ++d4) {
            const float4 w = *(const float4*)(&sm.c.sw[cc * 64 + d4 * 4]);
            acc[d4 * 4 + 0] = fmaf(pv[u], w.x, acc[d4 * 4 + 0]);
            acc[d4 * 4 + 1] = fmaf(pv[u], w.y, acc[d4 * 4 + 1]);
            acc[d4 * 4 + 2] = fmaf(pv[u], w.z, acc[d4 * 4 + 2]);
            acc[d4 * 4 + 3] = fmaf(pv[u], w.w, acc[d4 * 4 + 3]);
          }
        }
      }
      float* o = P1 + (size_t)r * 64;
#pragma unroll
      for (int d4 = 0; d4 < 16; ++d4)
        *(float4*)(o + d4 * 4) = make_float4(acc[d4 * 4 + 0], acc[d4 * 4 + 1],
                                             acc[d4 * 4 + 2], acc[d4 * 4 + 3]);
    }
    __syncthreads();  // all rows of this block complete (barrier drains vmcnt)
    if (t == 0) {
      __threadfence();
      __hip_atomic_fetch_add(p1done, 1, __ATOMIC_ACQ_REL, __HIP_MEMORY_SCOPE_AGENT);
    }
    // ---- wait for ALL P1 (finishes ~15us; first flag needed at ~40us) ----
    {
      int spins = 0;
      while (__hip_atomic_load(p1done, __ATOMIC_ACQUIRE, __HIP_MEMORY_SCOPE_AGENT) < nb &&
             ++spins < (1 << 20))
        __builtin_amdgcn_s_sleep(2);
    }
    const float r2 = (float)(0.2 * 0.2);  // double->f32 (NOT 0.2f*0.2f)
    // ---- chunk loop: 16 queries per chunk, ordered by center index ----
    for (int c = cb; c < NCHUNK; c += nb) {
      const int s16 = c >> 4, b = c & 15;
      const int q0 = b * NPOINT + s16 * 16;
      {  // wait for centers [.. s16*16+16) -- flag group s16>>2
        int spins = 0;
        while (__hip_atomic_load(&flags[b * 16 + (s16 >> 2)], __ATOMIC_ACQUIRE,
                                 __HIP_MEMORY_SCOPE_AGENT) == 0 &&
               ++spins < (1 << 20))
          __builtin_amdgcn_s_sleep(2);
      }
      const float* g = xyz + (size_t)b * NPTS * 3;
      // ---- ball query: wave wv handles local queries wv*2, wv*2+1 ----
      for (int s = 0; s < 2; ++s) {
        const int ql = wv * 2 + s;
        const int q = q0 + ql;
        const float nx = out_xyz[(size_t)q * 3];
        const float ny = out_xyz[(size_t)q * 3 + 1];
        const float nz = out_xyz[(size_t)q * 3 + 2];
        int cnt = 0;
        for (int base = 0; base < NPTS; base += 64) {
          const int j = base + lane;
          const float dx = __fsub_rn(g[3 * j], nx);
          const float dy = __fsub_rn(g[3 * j + 1], ny);
          const float dz = __fsub_rn(g[3 * j + 2], nz);
          const float d2 = __fadd_rn(__fadd_rn(__fmul_rn(dx, dx), __fmul_rn(dy, dy)),
                                     __fmul_rn(dz, dz));
          const bool hit = d2 <= r2;
          const unsigned long long m = __ballot(hit);
          const int pos = cnt + __popcll(m & ((1ull << lane) - 1ull));
          if (hit && pos < NSAMPLE) sm.c.sidx[ql][pos] = j;
          cnt += __popcll(m);
          if (cnt >= NSAMPLE) break;  // wave-uniform
        }
        const int capped = cnt < NSAMPLE ? cnt : NSAMPLE;
        if (lane < NSAMPLE) {
          const int v = sm.c.sidx[ql][lane < capped ? lane : 0];  // pad w/ first hit
          sm.c.sidx[ql][lane] = v;
          out_idx[(size_t)q * NSAMPLE + lane] = (float)v;
        }
      }
      __syncthreads();
      // ---- MLP + maxpool: 512 items = 16 q x 32 k, exactly one round ----
      const int k = t & 31;
      const int ql = t >> 5;
      const int q = q0 + ql;
      const int idx = sm.c.sidx[ql][k];
      const float nx = out_xyz[(size_t)q * 3];
      const float ny = out_xyz[(size_t)q * 3 + 1];
      const float nz = out_xyz[(size_t)q * 3 + 2];
      const float* p = g + (size_t)idx * 3;
      const float dx = p[0] - nx, dy = p[1] - ny, dz = p[2] - nz;

      float h1[64];
      const float* p1r = P1 + ((size_t)b * NPTS + idx) * 64;
#pragma unroll
      for (int d4 = 0; d4 < 16; ++d4) {
        const float4 pv = *(const float4*)(p1r + d4 * 4);
        const float pe[4] = {pv.x, pv.y, pv.z, pv.w};
#pragma unroll
        for (int u = 0; u < 4; ++u) {
          const int d = d4 * 4 + u;
          const float v = pe[u] + dx * W0[d] + dy * W0[64 + d] + dz * W0[128 + d] + b0[d];
          h1[d] = fmaxf(v, 0.0f);
        }
      }
      float h2[64];
#pragma unroll
      for (int j4 = 0; j4 < 16; ++j4) {
        const float4 bb = *(const float4*)(&b1[j4 * 4]);
        h2[j4 * 4 + 0] = bb.x; h2[j4 * 4 + 1] = bb.y;
        h2[j4 * 4 + 2] = bb.z; h2[j4 * 4 + 3] = bb.w;
      }
#pragma unroll
      for (int cc = 0; cc < 64; ++cc) {
        const float hc = h1[cc];
#pragma unroll
        for (int j4 = 0; j4 < 16; ++j4) {
          const float4 w = *(const float4*)(&W1[cc * 64 + j4 * 4]);
          h2[j4 * 4 + 0] = fmaf(hc, w.x, h2[j4 * 4 + 0]);
          h2[j4 * 4 + 1] = fmaf(hc, w.y, h2[j4 * 4 + 1]);
          h2[j4 * 4 + 2] = fmaf(hc, w.z, h2[j4 * 4 + 2]);
          h2[j4 * 4 + 3] = fmaf(hc, w.w, h2[j4 * 4 + 3]);
        }
      }
#pragma unroll
      for (int j = 0; j < 64; ++j) h2[j] = fmaxf(h2[j], 0.0f);

      float* outq = out_np + (size_t)q * 128;
      for (int jb = 0; jb < 4; ++jb) {
        float acc[32];
#pragma unroll
        for (int j8 = 0; j8 < 8; ++j8) {
          const float4 bb = *(const float4*)(&b2[jb * 32 + j8 * 4]);
          acc[j8 * 4 + 0] = bb.x; acc[j8 * 4 + 1] = bb.y;
          acc[j8 * 4 + 2] = bb.z; acc[j8 * 4 + 3] = bb.w;
        }
#pragma unroll
        for (int cc = 0; cc < 64; ++cc) {
          const float hc = h2[cc];
#pragma unroll
          for (int j8 = 0; j8 < 8; ++j8) {
            const float4 w = *(const float4*)(&W2[cc * 128 + jb * 32 + j8 * 4]);
            acc[j8 * 4 + 0] = fmaf(hc, w.x, acc[j8 * 4 + 0]);
            acc[j8 * 4 + 1] = fmaf(hc, w.y, acc[j8 * 4 + 1]);
            acc[j8 * 4 + 2] = fmaf(hc, w.z, acc[j8 * 4 + 2]);
            acc[j8 * 4 + 3] = fmaf(hc, w.w, acc[j8 * 4 + 3]);
          }
        }
#pragma unroll
        for (int j = 0; j < 32; ++j) acc[j] = fmaxf(acc[j], 0.0f);
#pragma unroll
        for (int msk = 16; msk >= 1; msk >>= 1) {
#pragma unroll
          for (int j = 0; j < 32; ++j)
            acc[j] = fmaxf(acc[j], __shfl_xor(acc[j], msk, 64));
        }
        if (k == 0) {
#pragma unroll
          for (int j8 = 0; j8 < 8; ++j8)
            *(float4*)(outq + jb * 32 + j8 * 4) =
                make_float4(acc[j8 * 4 + 0], acc[j8 * 4 + 1],
                            acc[j8 * 4 + 2], acc[j8 * 4 + 3]);
        }
      }
      __syncthreads();  // protect sidx before next chunk overwrites
    }
  }
}

extern "C" void kernel_launch(void* const* d_in, const int* in_sizes, int n_in,
                              void* d_out, int out_size, void* d_ws, size_t ws_size,
                              hipStream_t stream) {
  const float* xyz = (const float*)d_in[0];
  const float* pts = (const float*)d_in[1];
  const float* W0  = (const float*)d_in[2];
  const float* b0  = (const float*)d_in[3];
  const float* W1  = (const float*)d_in[4];
  const float* b1  = (const float*)d_in[5];
  const float* W2  = (const float*)d_in[6];
  const float* b2  = (const float*)d_in[7];

  float* out      = (float*)d_out;
  float* out_xyz  = out;                       // [16,1024,3]
  float* out_np   = out + 16 * 1024 * 3;       // [16,1024,128]
  float* out_idx  = out_np + 16 * 1024 * 128;  // [16,1024,32] as float values

  float* P1     = (float*)d_ws;                           // 16 MB
  int*   flags  = (int*)((char*)d_ws + (16u << 20));      // 256 ints
  int*   p1done = flags + 256;

  // zero sync state every call (replay-safe; memset is capture-legal)
  hipMemsetAsync(flags, 0, 2048, stream);

  void* args[] = {(void*)&xyz, (void*)&pts, (void*)&W0, (void*)&b0,
                  (void*)&W1,  (void*)&b1,  (void*)&W2, (void*)&b2,
                  (void*)&out_xyz, (void*)&out_np, (void*)&out_idx,
                  (void*)&P1, (void*)&flags, (void*)&p1done};
  hipLaunchCooperativeKernel((const void*)mega_kernel, dim3(256), dim3(512),
                             args, 0, stream);
}